// Round 12
// baseline (4445.102 us; speedup 1.0000x reference)
//
#include <hip/hip_runtime.h>

typedef short bf16x8 __attribute__((ext_vector_type(8)));
typedef float f32x4 __attribute__((ext_vector_type(4)));

#define LOG2E 1.44269504088896340736f

__device__ __forceinline__ unsigned short f2bf(float x) {
    unsigned u = __builtin_bit_cast(unsigned, x);
    return (unsigned short)((u + 0x7fffu + ((u >> 16) & 1u)) >> 16);
}

// 256 blocks x 1024 threads (1 block/CU, 16 waves). Producer/consumer wave
// specialization, round-12 fix: role = wave & 1 (was (wave>>2)&1 in r11).
// r11's counters (MfmaUtil+VALUBusy=83%<100, wall worse) indicate gfx950 maps
// CONTIGUOUS 4-wave groups to a SIMD, so r11's role assignment segregated
// whole SIMDs into pure-GEMM / pure-tail -> tail SIMDs carried 2x trans load.
// With role=wave&1, each SIMD gets 2 GEMM + 2 tail waves -> matrix pipe and
// trans pipe drain concurrently (m114 mechanism).
//   phase1: gates_A(t)=W'h_A(t-1)   ||  tail_B(t-1) [+outg_A every 8]
//   phase2: gates_B(t)=W'h_B(t-1)   ||  tail_A(t)   [+outg_B every 8]
// Math identical to r11 (passed, absmax 1.953e-3).
__global__ __launch_bounds__(1024, 4)
void lstm_persist(const float* __restrict__ zP, const float* __restrict__ condP,
                  const float* __restrict__ startP, const float* __restrict__ WihP,
                  const float* __restrict__ WhhP, const float* __restrict__ bihP,
                  const float* __restrict__ bhhP, const float* __restrict__ WoutP,
                  const float* __restrict__ boutP, float* __restrict__ outP)
{
    // LDS map (bytes):
    //   0      : gates[2 grp][512 gcol][16 row] f32, gcol stride 80  (81920)
    //   81920  : h rings, 2 grp x 8 slots x [16 row][128 col] bf16 swizzled (65536)
    //   147456 : wof fragments, 4 kt x 64 lanes x 16B (4096)
    __shared__ __align__(16) char lds[151552];

    const int tid  = threadIdx.x;
    const int wave = tid >> 6;
    const int lane = tid & 63;
    const int lo   = lane & 15;
    const int gq   = lane >> 4;
    const int r0   = blockIdx.x * 32;   // A: +0..15, B: +16..31
    const int role = wave & 1;          // 0=GEMM, 1=tail (mixed per SIMD under
                                        // contiguous wave->SIMD mapping)
    const int ridx = wave >> 1;         // 0..7 within role

    const float ss[4] = { -LOG2E, -LOG2E, 2.0f * LOG2E, -LOG2E };
    const float K2 = 2.0f * LOG2E;

    constexpr int GBUF  = 40960;    // per-group gates bytes
    constexpr int HB    = 81920;    // h rings base
    constexpr int HRING = 32768;    // per-group ring bytes
    constexpr int WOFB  = 147456;   // wof base

    int rdoff[4];   // h-ring A-fragment reads (swizzled), also used by outg
    #pragma unroll
    for (int kt = 0; kt < 4; ++kt)
        rdoff[kt] = (lo * 256 + kt * 64 + gq * 16) ^ ((lo & 7) << 4);

    if (role == 0) {
        // ================= GEMM waves =================
        const int hid0 = ridx * 16;
        bf16x8 bfrag[4][4];
        #pragma unroll
        for (int s = 0; s < 4; ++s) {
            const int col = s * 128 + hid0 + lo;
            const float wx0 = WihP[col * 39 + 0];
            const float wx1 = WihP[col * 39 + 1];
            #pragma unroll
            for (int kt = 0; kt < 4; ++kt) {
                bf16x8 f;
                #pragma unroll
                for (int j = 0; j < 8; ++j) {
                    const int k = kt * 32 + gq * 8 + j;
                    const float w = WhhP[col * 128 + k]
                                  + wx0 * WoutP[k] + wx1 * WoutP[128 + k];
                    f[j] = (short)f2bf(ss[s] * w);
                }
                bfrag[s][kt] = f;
            }
        }
        int gwoff[4];   // gates writes: [gcol][row] stride 80B, rows gq*4..+3
        #pragma unroll
        for (int s = 0; s < 4; ++s)
            gwoff[s] = (s * 128 + hid0 + lo) * 80 + gq * 16;

        __syncthreads();   // h(0) + wof ready

        #pragma unroll 1
        for (int t = 1; t < 2048; ++t) {
            const int sb = ((t - 1) & 7) * 4096;
            {   // phase 1: gates_A(t)
                const char* hb = lds + HB + sb;
                bf16x8 af[4];
                #pragma unroll
                for (int kt = 0; kt < 4; ++kt)
                    af[kt] = __builtin_bit_cast(bf16x8, *(const f32x4*)(hb + rdoff[kt]));
                #pragma unroll
                for (int s = 0; s < 4; ++s) {
                    f32x4 a = f32x4{0.f, 0.f, 0.f, 0.f};
                    #pragma unroll
                    for (int kt = 0; kt < 4; ++kt)
                        a = __builtin_amdgcn_mfma_f32_16x16x32_bf16(af[kt], bfrag[s][kt], a, 0, 0, 0);
                    *(f32x4*)(lds + gwoff[s]) = a;
                }
            }
            __syncthreads();
            {   // phase 2: gates_B(t)
                const char* hb = lds + HB + HRING + sb;
                bf16x8 af[4];
                #pragma unroll
                for (int kt = 0; kt < 4; ++kt)
                    af[kt] = __builtin_bit_cast(bf16x8, *(const f32x4*)(hb + rdoff[kt]));
                #pragma unroll
                for (int s = 0; s < 4; ++s) {
                    f32x4 a = f32x4{0.f, 0.f, 0.f, 0.f};
                    #pragma unroll
                    for (int kt = 0; kt < 4; ++kt)
                        a = __builtin_amdgcn_mfma_f32_16x16x32_bf16(af[kt], bfrag[s][kt], a, 0, 0, 0);
                    *(f32x4*)(lds + GBUF + gwoff[s]) = a;
                }
            }
            __syncthreads();
        }
        __syncthreads();   // epilogue (tail finishes h_B(2047))
        return;
    }

    // ================= tail waves =================
    const int hcol = ridx * 16 + lo;   // this lane's hidden column
    int groff[4], wroff[4];
    #pragma unroll
    for (int s = 0; s < 4; ++s)
        groff[s] = (s * 128 + hcol) * 80 + gq * 16;   // rows gq*4..gq*4+3
    #pragma unroll
    for (int i = 0; i < 4; ++i) {
        const int row = gq * 4 + i;
        wroff[i] = (row * 256 + hcol * 2) ^ ((row & 7) << 4);
    }
    const float bo = (lo < 2) ? boutP[lo] : 0.0f;

    // ---- static projection (r2 ordering), rows gq*4+i per lane ----
    f32x4 spA[4], spB[4];
    float wxs0[4], wxs1[4];
    {
        float w38[4];
        #pragma unroll
        for (int s = 0; s < 4; ++s) {
            const int col = s * 128 + hcol;
            const float b = bihP[col] + bhhP[col];
            wxs0[s] = ss[s] * WihP[col * 39 + 0];
            wxs1[s] = ss[s] * WihP[col * 39 + 1];
            w38[s]  = WihP[col * 39 + 38];
            #pragma unroll
            for (int i = 0; i < 4; ++i) { spA[s][i] = b; spB[s][i] = b; }
        }
        for (int j = 0; j < 32; ++j) {
            float w[4];
            #pragma unroll
            for (int s = 0; s < 4; ++s) w[s] = WihP[(s * 128 + hcol) * 39 + 2 + j];
            #pragma unroll
            for (int i = 0; i < 4; ++i) {
                const int rowA = r0 + gq * 4 + i;
                const float za = zP[rowA * 32 + j];
                const float zb = zP[(rowA + 16) * 32 + j];
                #pragma unroll
                for (int s = 0; s < 4; ++s) { spA[s][i] += za * w[s]; spB[s][i] += zb * w[s]; }
            }
        }
        for (int j = 0; j < 4; ++j) {
            float w[4];
            #pragma unroll
            for (int s = 0; s < 4; ++s) w[s] = WihP[(s * 128 + hcol) * 39 + 34 + j];
            #pragma unroll
            for (int i = 0; i < 4; ++i) {
                const int rowA = r0 + gq * 4 + i;
                const float ca = condP[rowA * 4 + j];
                const float cb = condP[(rowA + 16) * 4 + j];
                #pragma unroll
                for (int s = 0; s < 4; ++s) { spA[s][i] += ca * w[s]; spB[s][i] += cb * w[s]; }
            }
        }
        #pragma unroll
        for (int s = 0; s < 4; ++s)
            #pragma unroll
            for (int i = 0; i < 4; ++i) {
                spA[s][i] = ss[s] * (spA[s][i] + 0.05f * w38[s]);
                spB[s][i] = ss[s] * (spB[s][i] + 0.05f * w38[s]);
            }
    }

    f32x4 cstA = f32x4{0.f, 0.f, 0.f, 0.f};
    f32x4 cstB = f32x4{0.f, 0.f, 0.f, 0.f};

    // tail core: scaled gates (f32x4 over rows) -> c update -> h bf16 -> ring
    auto tailcore = [&](f32x4 (&g4)[4], f32x4& c, const int hbase) {
        float h[4];
        #pragma unroll
        for (int i = 0; i < 4; ++i) {
            const float si = __builtin_amdgcn_rcpf(1.0f + __builtin_amdgcn_exp2f(g4[0][i]));
            const float sf = __builtin_amdgcn_rcpf(1.0f + __builtin_amdgcn_exp2f(g4[1][i]));
            const float rg = __builtin_amdgcn_rcpf(1.0f + __builtin_amdgcn_exp2f(g4[2][i]));
            const float so = __builtin_amdgcn_rcpf(1.0f + __builtin_amdgcn_exp2f(g4[3][i]));
            const float tg = __builtin_fmaf(rg, -2.0f, 1.0f);
            const float cn = __builtin_fmaf(sf, c[i], si * tg);
            c[i] = cn;
            const float rc = __builtin_amdgcn_rcpf(1.0f + __builtin_amdgcn_exp2f(cn * K2));
            const float tc = __builtin_fmaf(rc, -2.0f, 1.0f);
            h[i] = so * tc;
        }
        unsigned p01, p23;
        asm("v_cvt_pk_bf16_f32 %0, %1, %2" : "=v"(p01) : "v"(h[0]), "v"(h[1]));
        asm("v_cvt_pk_bf16_f32 %0, %1, %2" : "=v"(p23) : "v"(h[2]), "v"(h[3]));
        *(unsigned short*)(lds + hbase + wroff[0]) = (unsigned short)(p01 & 0xffffu);
        *(unsigned short*)(lds + hbase + wroff[1]) = (unsigned short)(p01 >> 16);
        *(unsigned short*)(lds + hbase + wroff[2]) = (unsigned short)(p23 & 0xffffu);
        *(unsigned short*)(lds + hbase + wroff[3]) = (unsigned short)(p23 >> 16);
    };
    // read gates + sp, then tail core
    auto dotail = [&](const int gbase, const f32x4 (&spg)[4], f32x4& c, const int hbase) {
        f32x4 g4[4];
        #pragma unroll
        for (int s = 0; s < 4; ++s)
            g4[s] = *(const f32x4*)(lds + gbase + groff[s]) + spg[s];
        tailcore(g4, c, hbase);
    };
    // output GEMM for group X, steps tb..tb+7 (wave ridx handles step tb+ridx)
    auto dooutg = [&](const int X, const int tb) {
        const char* hb = lds + HB + X * HRING + ridx * 4096;
        f32x4 x = f32x4{0.f, 0.f, 0.f, 0.f};
        #pragma unroll
        for (int kt = 0; kt < 4; ++kt) {
            const bf16x8 a = __builtin_bit_cast(bf16x8, *(const f32x4*)(hb + rdoff[kt]));
            const bf16x8 w = __builtin_bit_cast(bf16x8, *(const f32x4*)(lds + WOFB + kt * 1024 + lane * 16));
            x = __builtin_amdgcn_mfma_f32_16x16x32_bf16(a, w, x, 0, 0, 0);
        }
        const int tg = tb + ridx;
        if (lo < 2) {
            #pragma unroll
            for (int rr = 0; rr < 4; ++rr)
                outP[(size_t)(r0 + X * 16 + gq * 4 + rr) * 4096 + tg * 2 + lo] = x[rr] + bo;
        }
    };

    // ---- wof fragments -> LDS (one tail wave; identical across waves) ----
    if (ridx == 0) {
        #pragma unroll
        for (int kt = 0; kt < 4; ++kt) {
            bf16x8 f;
            #pragma unroll
            for (int j = 0; j < 8; ++j) {
                const int k = kt * 32 + gq * 8 + j;
                f[j] = (lo < 2) ? (short)f2bf(WoutP[lo * 128 + k]) : (short)0;
            }
            *(bf16x8*)(lds + WOFB + kt * 1024 + lane * 16) = f;
        }
    }

    // ---- step 0 (pure VALU): gates0 = sp + ss*(x_start@Wx^T), then tail ----
    {
        f32x4 a0[4], b0[4];
        #pragma unroll
        for (int s = 0; s < 4; ++s) { a0[s] = spA[s]; b0[s] = spB[s]; }
        #pragma unroll
        for (int i = 0; i < 4; ++i) {
            const int rowA = r0 + gq * 4 + i;
            const float xa0 = startP[rowA * 2 + 0];
            const float xa1 = startP[rowA * 2 + 1];
            const float xb0 = startP[(rowA + 16) * 2 + 0];
            const float xb1 = startP[(rowA + 16) * 2 + 1];
            #pragma unroll
            for (int s = 0; s < 4; ++s) {
                a0[s][i] += xa0 * wxs0[s] + xa1 * wxs1[s];
                b0[s][i] += xb0 * wxs0[s] + xb1 * wxs1[s];
            }
        }
        tailcore(a0, cstA, HB + 0);            // h_A(0) -> A slot 0
        tailcore(b0, cstB, HB + HRING + 0);    // h_B(0) -> B slot 0
    }
    // fold bx = ss*(Wx@b_out) into sp for t >= 1
    #pragma unroll
    for (int s = 0; s < 4; ++s) {
        const float bx = wxs0[s] * boutP[0] + wxs1[s] * boutP[1];
        #pragma unroll
        for (int i = 0; i < 4; ++i) { spA[s][i] += bx; spB[s][i] += bx; }
    }
    __syncthreads();

    // ---- main pipeline ----
    #pragma unroll 1
    for (int t = 1; t < 2048; ++t) {
        const int sb = ((t - 1) & 7) * 4096;
        // phase 1: tail_B(t-1) (gates_B(t-1) from prev phase 2); outg_A when due
        if (t > 1)
            dotail(GBUF, spB, cstB, HB + HRING + sb);
        if ((t & 7) == 0) dooutg(0, t - 8);
        __syncthreads();
        // phase 2: tail_A(t) (gates_A(t) just produced); outg_B when due
        dotail(0, spA, cstA, HB + (t & 7) * 4096);
        if ((t & 7) == 0) dooutg(1, t - 8);
        __syncthreads();
    }

    // ---- epilogue: tail_B(2047) -> slot 7, then final output batches ----
    dotail(GBUF, spB, cstB, HB + HRING + 7 * 4096);
    __syncthreads();
    dooutg(0, 2040);
    dooutg(1, 2040);
}

extern "C" void kernel_launch(void* const* d_in, const int* in_sizes, int n_in,
                              void* d_out, int out_size, void* d_ws, size_t ws_size,
                              hipStream_t stream) {
    const float* z    = (const float*)d_in[0];
    const float* cond = (const float*)d_in[1];
    const float* strt = (const float*)d_in[2];
    const float* Wih  = (const float*)d_in[3];
    const float* Whh  = (const float*)d_in[4];
    const float* bih  = (const float*)d_in[5];
    const float* bhh  = (const float*)d_in[6];
    const float* Wout = (const float*)d_in[7];
    const float* bout = (const float*)d_in[8];
    float* out = (float*)d_out;

    hipLaunchKernelGGL(lstm_persist, dim3(256), dim3(1024), 0, stream,
                       z, cond, strt, Wih, Whh, bih, bhh, Wout, bout, out);
}

// Round 13
// 2852.923 us; speedup vs baseline: 1.5581x; 1.5581x over previous
//
#include <hip/hip_runtime.h>

typedef short bf16x8 __attribute__((ext_vector_type(8)));
typedef float f32x4 __attribute__((ext_vector_type(4)));

#define LOG2E 1.44269504088896340736f

__device__ __forceinline__ unsigned short f2bf(float x) {
    unsigned u = __builtin_bit_cast(unsigned, x);
    return (unsigned short)((u + 0x7fffu + ((u >> 16) & 1u)) >> 16);
}

// 256 blocks x 512 threads (1 block/CU). Block owns 32 batch rows as TWO
// independent 16-row groups (A,B) sharing weight registers. Group B is skewed
// half a step behind A:
//   phase1: MFMA-A(t) || tail-B(t-1)   -> barrier
//   phase2: MFMA-B(t) || tail-A(t) [+ output GEMM every 8 steps] -> barrier
// Rings are 16 deep so the output GEMM reads slots disjoint from concurrent
// writes (8 apart mod 16) -- no extra barrier. Best measured variant (r8:
// 2850 us). Session-final: specialization (r11/r12), SGB interleave (r9),
// barrier-halving (r10), tail algebra (r4/r5), unroll (r6) all measured worse.
__global__ __launch_bounds__(512, 2)
void lstm_persist(const float* __restrict__ zP, const float* __restrict__ condP,
                  const float* __restrict__ startP, const float* __restrict__ WihP,
                  const float* __restrict__ WhhP, const float* __restrict__ bihP,
                  const float* __restrict__ bhhP, const float* __restrict__ WoutP,
                  const float* __restrict__ boutP, float* __restrict__ outP)
{
    // two h history rings: 2 x (16 slots x 16 rows x 128 hidden) bf16, swizzled
    __shared__ unsigned short hist[2 * 16 * 16 * 128];   // 128 KiB
    char* const lds = (char*)hist;                       // group B at +65536

    const int tid  = threadIdx.x;
    const int wave = tid >> 6;
    const int lane = tid & 63;
    const int lo   = lane & 15;       // col within fragment
    const int gq   = lane >> 4;       // 0..3
    const int r0   = blockIdx.x * 32; // global batch-row base (A: +0, B: +16)
    const int hid0 = wave * 16;       // this wave's hidden slice

    const float K2 = 2.0f * LOG2E;
    const float ss[4] = { -LOG2E, -LOG2E, 2.0f * LOG2E, -LOG2E };

    // ---- B fragments of W' = ss[s]*(W_hh + Wx @ W_out)  (bf16, registers) ----
    float wxs0[4], wxs1[4], bias[4];
    bf16x8 bfrag[4][4];
    #pragma unroll
    for (int s = 0; s < 4; ++s) {
        const int col = s * 128 + hid0 + lo;
        const float wx0 = WihP[col * 39 + 0];
        const float wx1 = WihP[col * 39 + 1];
        wxs0[s] = ss[s] * wx0;
        wxs1[s] = ss[s] * wx1;
        bias[s] = bihP[col] + bhhP[col];
        #pragma unroll
        for (int kt = 0; kt < 4; ++kt) {
            bf16x8 f;
            #pragma unroll
            for (int j = 0; j < 8; ++j) {
                const int k = kt * 32 + gq * 8 + j;
                const float w = WhhP[col * 128 + k]
                              + wx0 * WoutP[k] + wx1 * WoutP[128 + k];
                f[j] = (short)f2bf(ss[s] * w);
            }
            bfrag[s][kt] = f;
        }
    }

    // ---- W_out B-fragments for the batched output GEMM ----
    bf16x8 wof[4];
    #pragma unroll
    for (int kt = 0; kt < 4; ++kt) {
        bf16x8 f;
        #pragma unroll
        for (int j = 0; j < 8; ++j) {
            const int k = kt * 32 + gq * 8 + j;
            f[j] = (lo < 2) ? (short)f2bf(WoutP[lo * 128 + k]) : (short)0;
        }
        wof[kt] = f;
    }
    const float bo = (lo < 2) ? boutP[lo] : 0.0f;

    // ---- static projection for both groups (C-fragment layout, pre-scaled) --
    f32x4 spA[4], spB[4];  // [strip], components = rr (row = grp + gq*4+rr)
    #pragma unroll
    for (int s = 0; s < 4; ++s)
        #pragma unroll
        for (int rr = 0; rr < 4; ++rr) { spA[s][rr] = bias[s]; spB[s][rr] = bias[s]; }

    for (int j = 0; j < 32; ++j) {   // z part
        float w[4];
        #pragma unroll
        for (int s = 0; s < 4; ++s) w[s] = WihP[(s * 128 + hid0 + lo) * 39 + 2 + j];
        #pragma unroll
        for (int rr = 0; rr < 4; ++rr) {
            const int rowA = r0 + gq * 4 + rr;
            const float sa = zP[rowA * 32 + j];
            const float sb = zP[(rowA + 16) * 32 + j];
            #pragma unroll
            for (int s = 0; s < 4; ++s) { spA[s][rr] += sa * w[s]; spB[s][rr] += sb * w[s]; }
        }
    }
    for (int j = 0; j < 4; ++j) {    // condition part
        float w[4];
        #pragma unroll
        for (int s = 0; s < 4; ++s) w[s] = WihP[(s * 128 + hid0 + lo) * 39 + 34 + j];
        #pragma unroll
        for (int rr = 0; rr < 4; ++rr) {
            const int rowA = r0 + gq * 4 + rr;
            const float sa = condP[rowA * 4 + j];
            const float sb = condP[(rowA + 16) * 4 + j];
            #pragma unroll
            for (int s = 0; s < 4; ++s) { spA[s][rr] += sa * w[s]; spB[s][rr] += sb * w[s]; }
        }
    }
    #pragma unroll
    for (int s = 0; s < 4; ++s) {    // dt term + scale
        const float w = 0.05f * WihP[(s * 128 + hid0 + lo) * 39 + 38];
        #pragma unroll
        for (int rr = 0; rr < 4; ++rr) {
            spA[s][rr] = ss[s] * (spA[s][rr] + w);
            spB[s][rr] = ss[s] * (spB[s][rr] + w);
        }
    }

    // ---- LDS offsets (swizzle: byte ^= (row&7)<<4) ----
    int wroff[4];
    #pragma unroll
    for (int rr = 0; rr < 4; ++rr) {
        const int row = gq * 4 + rr;
        wroff[rr] = (row * 256 + (hid0 + lo) * 2) ^ ((row & 7) << 4);
    }
    int rdoff[4];
    #pragma unroll
    for (int kt = 0; kt < 4; ++kt)
        rdoff[kt] = (lo * 256 + kt * 64 + gq * 16) ^ ((lo & 7) << 4);

    // ---- LSTM cell state (per group) + pipelined gate accumulators ----
    f32x4 cstA = f32x4{0.f, 0.f, 0.f, 0.f};
    f32x4 cstB = f32x4{0.f, 0.f, 0.f, 0.f};
    f32x4 accA[4], accB[4];

    // activation tail (round-2 math): scaled gates -> h bf16 -> LDS, updates c
    auto tail = [&](f32x4 (&acc)[4], f32x4& cst, const int wbyte) {
        float h[4];
        #pragma unroll
        for (int rr = 0; rr < 4; ++rr) {
            const float si = __builtin_amdgcn_rcpf(1.0f + __builtin_amdgcn_exp2f(acc[0][rr]));
            const float sf = __builtin_amdgcn_rcpf(1.0f + __builtin_amdgcn_exp2f(acc[1][rr]));
            const float rg = __builtin_amdgcn_rcpf(1.0f + __builtin_amdgcn_exp2f(acc[2][rr]));
            const float so = __builtin_amdgcn_rcpf(1.0f + __builtin_amdgcn_exp2f(acc[3][rr]));
            const float tg = __builtin_fmaf(rg, -2.0f, 1.0f);
            const float cn = __builtin_fmaf(sf, cst[rr], si * tg);
            cst[rr] = cn;
            const float rc = __builtin_amdgcn_rcpf(1.0f + __builtin_amdgcn_exp2f(cn * K2));
            const float tc = __builtin_fmaf(rc, -2.0f, 1.0f);
            h[rr] = so * tc;
        }
        unsigned p01, p23;
        asm("v_cvt_pk_bf16_f32 %0, %1, %2" : "=v"(p01) : "v"(h[0]), "v"(h[1]));
        asm("v_cvt_pk_bf16_f32 %0, %1, %2" : "=v"(p23) : "v"(h[2]), "v"(h[3]));
        *(unsigned short*)(lds + wbyte + wroff[0]) = (unsigned short)(p01 & 0xffffu);
        *(unsigned short*)(lds + wbyte + wroff[1]) = (unsigned short)(p01 >> 16);
        *(unsigned short*)(lds + wbyte + wroff[2]) = (unsigned short)(p23 & 0xffffu);
        *(unsigned short*)(lds + wbyte + wroff[3]) = (unsigned short)(p23 >> 16);
    };

    // batched output GEMM for steps tb..tb+7 (slots (tb&15)..(tb&15)+7,
    // both groups); wave w handles step tb+w. Reads are 8 slots apart (mod 16)
    // from any concurrent tail write -> no barrier needed around it.
    auto outg = [&](const int tb) {
        const int sbase = ((tb & 15) + wave) * 4096;
        f32x4 xa = f32x4{0.f, 0.f, 0.f, 0.f};
        f32x4 xb = f32x4{0.f, 0.f, 0.f, 0.f};
        #pragma unroll
        for (int kt = 0; kt < 4; ++kt) {
            const bf16x8 a = __builtin_bit_cast(bf16x8,
                *(const f32x4*)(lds + sbase + rdoff[kt]));
            xa = __builtin_amdgcn_mfma_f32_16x16x32_bf16(a, wof[kt], xa, 0, 0, 0);
            const bf16x8 b = __builtin_bit_cast(bf16x8,
                *(const f32x4*)(lds + 65536 + sbase + rdoff[kt]));
            xb = __builtin_amdgcn_mfma_f32_16x16x32_bf16(b, wof[kt], xb, 0, 0, 0);
        }
        const int tg = tb + wave;
        if (lo < 2) {
            #pragma unroll
            for (int rr = 0; rr < 4; ++rr) {
                const int row = gq * 4 + rr;
                outP[(size_t)(r0 + row) * 4096 + tg * 2 + lo] = xa[rr] + bo;
                outP[(size_t)(r0 + 16 + row) * 4096 + tg * 2 + lo] = xb[rr] + bo;
            }
        }
    };

    // ---- step 0 for both groups (pure VALU, h0 = c0 = 0) ----
    {
        f32x4 accA0[4];
        #pragma unroll
        for (int s = 0; s < 4; ++s) { accA0[s] = spA[s]; accB[s] = spB[s]; }
        #pragma unroll
        for (int rr = 0; rr < 4; ++rr) {
            const int rowA = r0 + gq * 4 + rr;
            const float a0 = startP[rowA * 2 + 0];
            const float a1 = startP[rowA * 2 + 1];
            const float b0 = startP[(rowA + 16) * 2 + 0];
            const float b1 = startP[(rowA + 16) * 2 + 1];
            #pragma unroll
            for (int s = 0; s < 4; ++s) {
                accA0[s][rr] += a0 * wxs0[s] + a1 * wxs1[s];
                accB[s][rr]  += b0 * wxs0[s] + b1 * wxs1[s];
            }
        }
        tail(accA0, cstA, 0);   // group A, slot 0; accB(0) stays in registers
    }
    // fold bx = ss*(Wx@b_out) into sp for t >= 1
    #pragma unroll
    for (int s = 0; s < 4; ++s) {
        const float bx = wxs0[s] * boutP[0] + wxs1[s] * boutP[1];
        #pragma unroll
        for (int rr = 0; rr < 4; ++rr) { spA[s][rr] += bx; spB[s][rr] += bx; }
    }
    __syncthreads();

    // ---- main recurrence: two skewed phases per step ----
    #pragma unroll 1
    for (int t = 1; t < 2048; ++t) {
        const int rb = ((t - 1) & 15) * 4096;

        // phase 1: MFMA-A(t) from h_A(t-1)  ||  tail-B(t-1) (VALU)
        bf16x8 afA[4];
        #pragma unroll
        for (int kt = 0; kt < 4; ++kt)
            afA[kt] = __builtin_bit_cast(bf16x8, *(const f32x4*)(lds + rb + rdoff[kt]));
        #pragma unroll
        for (int s = 0; s < 4; ++s) {
            f32x4 a = spA[s];
            #pragma unroll
            for (int kt = 0; kt < 4; ++kt)
                a = __builtin_amdgcn_mfma_f32_16x16x32_bf16(afA[kt], bfrag[s][kt], a, 0, 0, 0);
            accA[s] = a;
        }
        tail(accB, cstB, 65536 + rb);          // writes h_B(t-1)
        __syncthreads();

        // phase 2: MFMA-B(t) from h_B(t-1)  ||  tail-A(t) (VALU) [+ outg]
        bf16x8 afB[4];
        #pragma unroll
        for (int kt = 0; kt < 4; ++kt)
            afB[kt] = __builtin_bit_cast(bf16x8, *(const f32x4*)(lds + 65536 + rb + rdoff[kt]));
        #pragma unroll
        for (int s = 0; s < 4; ++s) {
            f32x4 a = spB[s];
            #pragma unroll
            for (int kt = 0; kt < 4; ++kt)
                a = __builtin_amdgcn_mfma_f32_16x16x32_bf16(afB[kt], bfrag[s][kt], a, 0, 0, 0);
            accB[s] = a;
        }
        tail(accA, cstA, (t & 15) * 4096);     // writes h_A(t)
        if ((t & 7) == 0) outg(t - 8);         // steps t-8..t-1, both groups
        __syncthreads();
    }

    // ---- epilogue: finish group B's step 2047, then last output batch ----
    tail(accB, cstB, 65536 + 15 * 4096);       // h_B(2047), slot 15
    __syncthreads();
    outg(2040);                                // steps 2040..2047 (slots 8..15)
}

extern "C" void kernel_launch(void* const* d_in, const int* in_sizes, int n_in,
                              void* d_out, int out_size, void* d_ws, size_t ws_size,
                              hipStream_t stream) {
    const float* z    = (const float*)d_in[0];
    const float* cond = (const float*)d_in[1];
    const float* strt = (const float*)d_in[2];
    const float* Wih  = (const float*)d_in[3];
    const float* Whh  = (const float*)d_in[4];
    const float* bih  = (const float*)d_in[5];
    const float* bhh  = (const float*)d_in[6];
    const float* Wout = (const float*)d_in[7];
    const float* bout = (const float*)d_in[8];
    float* out = (float*)d_out;

    hipLaunchKernelGGL(lstm_persist, dim3(256), dim3(512), 0, stream,
                       z, cond, strt, Wih, Whh, bih, bhh, Wout, bout, out);
}